// Round 1
// baseline (268.985 us; speedup 1.0000x reference)
//
#include <hip/hip_runtime.h>
#include <math.h>

#define CAP2  512            // max in-edges of target node (expected ~16)
#define CAPS1 (CAP2 + 1)     // max 1-hop node set size
#define CAP1  65536          // max edges into S1 nodes (expected ~300)
#define CAPN  512            // per-node in-edge cap inside layer-1 kernel

// ---------------------------------------------------------------------------
// header layout in workspace (ints): [0]=cnt2 [1]=cnt1 [2]=n_s1 [3]=nE2
// [4]=ea_sum (float bits)
// ---------------------------------------------------------------------------

__global__ void k_init(int* hdr, int* node2idx, int N) {
    int i = blockIdx.x * blockDim.x + threadIdx.x;
    if (i < 8) hdr[i] = 0;               // 0 bits == 0.0f for ea_sum too
    for (int j = i; j < N; j += gridDim.x * blockDim.x) node2idx[j] = -1;
}

// scan 1: find in-edges of target t; reduce sum(edge_attr)
__global__ void k_scanA(const int* __restrict__ ei, const float* __restrict__ ea,
                        const int* __restrict__ tptr, int E,
                        int* hdr, int* L2_src, float* L2_ea) {
    int t = tptr[0];
    float local = 0.f;
    int stride = gridDim.x * blockDim.x;
    for (int e = blockIdx.x * blockDim.x + threadIdx.x; e < E; e += stride) {
        float a = ea[e];
        local += a;
        int d = ei[E + e];
        if (d == t) {
            int p = atomicAdd(&hdr[0], 1);
            if (p < CAP2) { L2_src[p] = ei[e]; L2_ea[p] = a; }
        }
    }
    for (int o = 32; o >= 1; o >>= 1) local += __shfl_xor(local, o, 64);
    if ((threadIdx.x & 63) == 0) atomicAdd((float*)&hdr[4], local);
}

// build S1 node set + node->index map (serial, tiny)
__global__ void k_build(const int* __restrict__ tptr, int* hdr,
                        const int* __restrict__ L2_src,
                        int* L2_s1idx, int* node2idx, int* S1nodes) {
    if (threadIdx.x != 0 || blockIdx.x != 0) return;
    int t = tptr[0];
    node2idx[t] = 0;
    S1nodes[0] = t;
    int n = 1;
    int c2 = hdr[0]; if (c2 > CAP2) c2 = CAP2;
    for (int k = 0; k < c2; k++) {
        int v = L2_src[k];
        int idx = node2idx[v];
        if (idx < 0) { idx = n; node2idx[v] = n; S1nodes[n] = v; n++; }
        L2_s1idx[k] = idx;
    }
    hdr[2] = n;
    hdr[3] = c2;
}

// scan 2: collect all edges whose dst is in S1
__global__ void k_scanC(const int* __restrict__ ei, const float* __restrict__ ea,
                        int E, const int* __restrict__ node2idx,
                        int* hdr, int* L1_src, int* L1_dst, float* L1_ea) {
    int stride = gridDim.x * blockDim.x;
    for (int e = blockIdx.x * blockDim.x + threadIdx.x; e < E; e += stride) {
        int d = ei[E + e];
        int idx = node2idx[d];
        if (idx >= 0) {
            int p = atomicAdd(&hdr[1], 1);
            if (p < CAP1) { L1_src[p] = ei[e]; L1_dst[p] = idx; L1_ea[p] = ea[e]; }
        }
    }
}

// layer 1: one 64-lane wave per S1 node; lane = output channel
__global__ __launch_bounds__(64)
void k_layer1(const float* __restrict__ x,
              const float* __restrict__ Wl1, const float* __restrict__ bl1,
              const float* __restrict__ Wr1, const float* __restrict__ br1,
              const float* __restrict__ We1, const float* __restrict__ att1,
              const float* __restrict__ b1,
              const int* __restrict__ hdr, const int* __restrict__ S1nodes,
              const int* __restrict__ L1_src, const int* __restrict__ L1_dst,
              const float* __restrict__ L1_ea,
              float* __restrict__ h1, int E) {
    int bi = blockIdx.x;
    if (bi >= hdr[2]) return;
    int lane = threadIdx.x;
    int v = S1nodes[bi];
    float eam = ((const float*)hdr)[4] / (float)E;

    float wl0 = Wl1[lane], wl1w = Wl1[64 + lane], bl = bl1[lane];
    float we = We1[lane], at = att1[lane];
    float xr = x[2 * v] * Wr1[lane] + x[2 * v + 1] * Wr1[64 + lane] + br1[lane];

    __shared__ int   esrc[CAPN + 1];
    __shared__ float eea[CAPN + 1];
    __shared__ float scores[CAPN + 1];
    __shared__ int   scnt;
    if (lane == 0) scnt = 0;
    __syncthreads();

    int c1 = hdr[1]; if (c1 > CAP1) c1 = CAP1;
    for (int k = lane; k < c1; k += 64) {
        if (L1_dst[k] == bi) {
            int p = atomicAdd(&scnt, 1);
            if (p < CAPN) { esrc[p] = L1_src[k]; eea[p] = L1_ea[k]; }
        }
    }
    __syncthreads();
    int nE = scnt; if (nE > CAPN) nE = CAPN;
    if (lane == 0) { esrc[nE] = v; eea[nE] = eam; }   // self-loop
    __syncthreads();
    nE += 1;

    // phase 1: attention scores
    for (int k = 0; k < nE; k++) {
        int s = esrc[k];
        float xl = x[2 * s] * wl0 + x[2 * s + 1] * wl1w + bl;
        float ev = xl + xr + eea[k] * we;
        ev = ev > 0.f ? ev : 0.2f * ev;
        float p = ev * at;
        for (int o = 32; o >= 1; o >>= 1) p += __shfl_xor(p, o, 64);
        if (lane == 0) scores[k] = p;
    }
    __syncthreads();

    float m = -3.4e38f;
    for (int k = lane; k < nE; k += 64) m = fmaxf(m, scores[k]);
    for (int o = 32; o >= 1; o >>= 1) m = fmaxf(m, __shfl_xor(m, o, 64));
    float dsum = 0.f;
    for (int k = lane; k < nE; k += 64) dsum += expf(scores[k] - m);
    for (int o = 32; o >= 1; o >>= 1) dsum += __shfl_xor(dsum, o, 64);

    // phase 2: weighted sum of source transforms
    float acc = 0.f;
    for (int k = 0; k < nE; k++) {
        int s = esrc[k];
        float xl = x[2 * s] * wl0 + x[2 * s + 1] * wl1w + bl;
        acc += (expf(scores[k] - m) / dsum) * xl;
    }
    float h = acc + b1[lane];
    h1[bi * 64 + lane] = h > 0.f ? h : 0.f;
}

// layer 2 at target + final head; one 64-lane wave
__global__ __launch_bounds__(64)
void k_layer2(const float* __restrict__ Wl2, const float* __restrict__ bl2,
              const float* __restrict__ Wr2, const float* __restrict__ br2,
              const float* __restrict__ We2, const float* __restrict__ att2,
              const float* __restrict__ b2,
              const float* __restrict__ Wf, const float* __restrict__ bf,
              const int* __restrict__ hdr,
              const int* __restrict__ L2_s1idx, const float* __restrict__ L2_ea,
              const float* __restrict__ h1, int E,
              float* __restrict__ out) {
    int lane = threadIdx.x;
    float eam = ((const float*)hdr)[4] / (float)E;
    int nE2 = hdr[3];   // real in-edges of t; self-loop appended as index nE2

    // target transform (target is S1 index 0)
    float xr = br2[lane];
    for (int k = 0; k < 64; k++) xr += h1[k] * Wr2[k * 64 + lane];

    __shared__ float scores[CAP2 + 1];
    __shared__ float h2sh[64];
    float we = We2[lane], at = att2[lane];

    for (int j = 0; j <= nE2; j++) {
        int   idx = (j < nE2) ? L2_s1idx[j] : 0;
        float eav = (j < nE2) ? L2_ea[j]    : eam;
        const float* hrow = h1 + idx * 64;
        float xl = bl2[lane];
        for (int k = 0; k < 64; k++) xl += hrow[k] * Wl2[k * 64 + lane];
        float ev = xl + xr + eav * we;
        ev = ev > 0.f ? ev : 0.2f * ev;
        float p = ev * at;
        for (int o = 32; o >= 1; o >>= 1) p += __shfl_xor(p, o, 64);
        if (lane == 0) scores[j] = p;
    }
    __syncthreads();

    int tot = nE2 + 1;
    float m = -3.4e38f;
    for (int j = lane; j < tot; j += 64) m = fmaxf(m, scores[j]);
    for (int o = 32; o >= 1; o >>= 1) m = fmaxf(m, __shfl_xor(m, o, 64));
    float dsum = 0.f;
    for (int j = lane; j < tot; j += 64) dsum += expf(scores[j] - m);
    for (int o = 32; o >= 1; o >>= 1) dsum += __shfl_xor(dsum, o, 64);

    float acc = 0.f;
    for (int j = 0; j <= nE2; j++) {
        int idx = (j < nE2) ? L2_s1idx[j] : 0;
        const float* hrow = h1 + idx * 64;
        float xl = bl2[lane];
        for (int k = 0; k < 64; k++) xl += hrow[k] * Wl2[k * 64 + lane];
        acc += (expf(scores[j] - m) / dsum) * xl;
    }
    float h = acc + b2[lane];
    h2sh[lane] = h > 0.f ? h : 0.f;
    __syncthreads();

    // final head: [64] @ [64,128] + bf
    for (int o = lane; o < 128; o += 64) {
        float r = bf[o];
        for (int c = 0; c < 64; c++) r += h2sh[c] * Wf[c * 128 + o];
        out[o] = r;
    }
}

extern "C" void kernel_launch(void* const* d_in, const int* in_sizes, int n_in,
                              void* d_out, int out_size, void* d_ws, size_t ws_size,
                              hipStream_t stream) {
    const float* x    = (const float*)d_in[0];
    const int*   ei   = (const int*)  d_in[1];
    const float* ea   = (const float*)d_in[2];
    const int*   tptr = (const int*)  d_in[3];
    const float* Wl1  = (const float*)d_in[4];
    const float* bl1  = (const float*)d_in[5];
    const float* Wr1  = (const float*)d_in[6];
    const float* br1  = (const float*)d_in[7];
    const float* We1  = (const float*)d_in[8];
    const float* att1 = (const float*)d_in[9];
    const float* b1   = (const float*)d_in[10];
    const float* Wl2  = (const float*)d_in[11];
    const float* bl2  = (const float*)d_in[12];
    const float* Wr2  = (const float*)d_in[13];
    const float* br2  = (const float*)d_in[14];
    const float* We2  = (const float*)d_in[15];
    const float* att2 = (const float*)d_in[16];
    const float* b2   = (const float*)d_in[17];
    const float* Wf   = (const float*)d_in[18];
    const float* bf   = (const float*)d_in[19];

    int N = in_sizes[0] / 2;
    int E = in_sizes[2];

    char* base = (char*)d_ws;
    int*   hdr      = (int*)base;   base += 256;
    int*   node2idx = (int*)base;   base += (size_t)N * sizeof(int);
    int*   S1nodes  = (int*)base;   base += CAPS1 * sizeof(int);
    int*   L2_src   = (int*)base;   base += CAP2 * sizeof(int);
    int*   L2_s1idx = (int*)base;   base += CAP2 * sizeof(int);
    float* L2_ea    = (float*)base; base += CAP2 * sizeof(float);
    int*   L1_src   = (int*)base;   base += CAP1 * sizeof(int);
    int*   L1_dst   = (int*)base;   base += CAP1 * sizeof(int);
    float* L1_ea    = (float*)base; base += CAP1 * sizeof(float);
    float* h1       = (float*)base; base += (size_t)CAPS1 * 64 * sizeof(float);

    hipLaunchKernelGGL(k_init, dim3((N + 255) / 256), dim3(256), 0, stream,
                       hdr, node2idx, N);
    hipLaunchKernelGGL(k_scanA, dim3(1024), dim3(256), 0, stream,
                       ei, ea, tptr, E, hdr, L2_src, L2_ea);
    hipLaunchKernelGGL(k_build, dim3(1), dim3(64), 0, stream,
                       tptr, hdr, L2_src, L2_s1idx, node2idx, S1nodes);
    hipLaunchKernelGGL(k_scanC, dim3(1024), dim3(256), 0, stream,
                       ei, ea, E, node2idx, hdr, L1_src, L1_dst, L1_ea);
    hipLaunchKernelGGL(k_layer1, dim3(CAPS1), dim3(64), 0, stream,
                       x, Wl1, bl1, Wr1, br1, We1, att1, b1,
                       hdr, S1nodes, L1_src, L1_dst, L1_ea, h1, E);
    hipLaunchKernelGGL(k_layer2, dim3(1), dim3(64), 0, stream,
                       Wl2, bl2, Wr2, br2, We2, att2, b2, Wf, bf,
                       hdr, L2_s1idx, L2_ea, h1, E, (float*)d_out);
}

// Round 2
// 202.018 us; speedup vs baseline: 1.3315x; 1.3315x over previous
//
#include <hip/hip_runtime.h>
#include <math.h>

#define CAP2  512            // max in-edges of target node (expected ~16)
#define CAPS1 (CAP2 + 1)     // max 1-hop node set size
#define CAP1  65536          // max edges into S1 nodes (expected ~300)
#define CAPN  512            // per-node in-edge cap inside layer-1 kernel

// header (ints): [0]=cnt2 [1]=cnt1 [2]=n_s1 [3]=nE2 [4]=ea_sum(float bits)

__global__ void k_init(int* hdr, int* node2idx, int N) {
    int i = blockIdx.x * blockDim.x + threadIdx.x;
    if (i < 8) hdr[i] = 0;
    for (int j = i; j < N; j += gridDim.x * blockDim.x) node2idx[j] = -1;
}

// scan 1 (vectorized): find in-edges of target t; reduce sum(edge_attr)
__global__ void k_scanA(const int* __restrict__ ei, const float* __restrict__ ea,
                        const int* __restrict__ tptr, int E,
                        int* hdr, int* L2_src, float* L2_ea) {
    int t = tptr[0];
    float local = 0.f;
    int stride = gridDim.x * blockDim.x;
    int gid = blockIdx.x * blockDim.x + threadIdx.x;
    const int4*   dst4 = (const int4*)(ei + E);
    const float4* ea4  = (const float4*)ea;
    int E4 = E >> 2;
    for (int e4 = gid; e4 < E4; e4 += stride) {
        int4 d = dst4[e4];
        float4 a = ea4[e4];
        local += a.x + a.y + a.z + a.w;
        int eb = e4 * 4;
        if (d.x == t) { int p = atomicAdd(&hdr[0], 1); if (p < CAP2) { L2_src[p] = ei[eb];     L2_ea[p] = a.x; } }
        if (d.y == t) { int p = atomicAdd(&hdr[0], 1); if (p < CAP2) { L2_src[p] = ei[eb + 1]; L2_ea[p] = a.y; } }
        if (d.z == t) { int p = atomicAdd(&hdr[0], 1); if (p < CAP2) { L2_src[p] = ei[eb + 2]; L2_ea[p] = a.z; } }
        if (d.w == t) { int p = atomicAdd(&hdr[0], 1); if (p < CAP2) { L2_src[p] = ei[eb + 3]; L2_ea[p] = a.w; } }
    }
    if (gid == 0) {                      // tail (E % 4)
        for (int e = E4 * 4; e < E; e++) {
            float a = ea[e];
            local += a;
            if (ei[E + e] == t) { int p = atomicAdd(&hdr[0], 1); if (p < CAP2) { L2_src[p] = ei[e]; L2_ea[p] = a; } }
        }
    }
    for (int o = 32; o >= 1; o >>= 1) local += __shfl_xor(local, o, 64);
    if ((threadIdx.x & 63) == 0) atomicAdd((float*)&hdr[4], local);
}

// build S1 node set + node->index map (serial, tiny)
__global__ void k_build(const int* __restrict__ tptr, int* hdr,
                        const int* __restrict__ L2_src,
                        int* L2_s1idx, int* node2idx, int* S1nodes) {
    if (threadIdx.x != 0 || blockIdx.x != 0) return;
    int t = tptr[0];
    node2idx[t] = 0;
    S1nodes[0] = t;
    int n = 1;
    int c2 = hdr[0]; if (c2 > CAP2) c2 = CAP2;
    for (int k = 0; k < c2; k++) {
        int v = L2_src[k];
        int idx = node2idx[v];
        if (idx < 0) { idx = n; node2idx[v] = n; S1nodes[n] = v; n++; }
        L2_s1idx[k] = idx;
    }
    hdr[2] = n;
    hdr[3] = c2;
}

// scan 2 (vectorized): collect all edges whose dst is in S1
__global__ void k_scanC(const int* __restrict__ ei, const float* __restrict__ ea,
                        int E, const int* __restrict__ node2idx,
                        int* hdr, int* L1_src, int* L1_dst, float* L1_ea) {
    int stride = gridDim.x * blockDim.x;
    int gid = blockIdx.x * blockDim.x + threadIdx.x;
    const int4* dst4 = (const int4*)(ei + E);
    int E4 = E >> 2;
    for (int e4 = gid; e4 < E4; e4 += stride) {
        int4 d = dst4[e4];
        int eb = e4 * 4;
        int i0 = node2idx[d.x], i1 = node2idx[d.y], i2 = node2idx[d.z], i3 = node2idx[d.w];
        if (i0 >= 0) { int p = atomicAdd(&hdr[1], 1); if (p < CAP1) { L1_src[p] = ei[eb];     L1_dst[p] = i0; L1_ea[p] = ea[eb];     } }
        if (i1 >= 0) { int p = atomicAdd(&hdr[1], 1); if (p < CAP1) { L1_src[p] = ei[eb + 1]; L1_dst[p] = i1; L1_ea[p] = ea[eb + 1]; } }
        if (i2 >= 0) { int p = atomicAdd(&hdr[1], 1); if (p < CAP1) { L1_src[p] = ei[eb + 2]; L1_dst[p] = i2; L1_ea[p] = ea[eb + 2]; } }
        if (i3 >= 0) { int p = atomicAdd(&hdr[1], 1); if (p < CAP1) { L1_src[p] = ei[eb + 3]; L1_dst[p] = i3; L1_ea[p] = ea[eb + 3]; } }
    }
    if (gid == 0) {
        for (int e = E4 * 4; e < E; e++) {
            int idx = node2idx[ei[E + e]];
            if (idx >= 0) { int p = atomicAdd(&hdr[1], 1); if (p < CAP1) { L1_src[p] = ei[e]; L1_dst[p] = idx; L1_ea[p] = ea[e]; } }
        }
    }
}

// layer 1: one 256-thread block (4 waves) per S1 node; lane = output channel,
// edges split across waves; x gathered into LDS in one parallel burst.
__global__ __launch_bounds__(256)
void k_layer1(const float* __restrict__ x,
              const float* __restrict__ Wl1, const float* __restrict__ bl1,
              const float* __restrict__ Wr1, const float* __restrict__ br1,
              const float* __restrict__ We1, const float* __restrict__ att1,
              const float* __restrict__ b1,
              const int* __restrict__ hdr, const int* __restrict__ S1nodes,
              const int* __restrict__ L1_src, const int* __restrict__ L1_dst,
              const float* __restrict__ L1_ea,
              float* __restrict__ h1, int E) {
    int bi = blockIdx.x;
    if (bi >= hdr[2]) return;
    int tid = threadIdx.x, lane = tid & 63, wq = tid >> 6;
    int v = S1nodes[bi];
    float eam = ((const float*)hdr)[4] / (float)E;

    __shared__ int   esrc[CAPN + 1];
    __shared__ float eea[CAPN + 1];
    __shared__ float xsA[CAPN + 1], xsB[CAPN + 1];
    __shared__ float scores[CAPN + 1];
    __shared__ float part[4][64];
    __shared__ float m_sh, d_sh;
    __shared__ int   scnt;
    if (tid == 0) scnt = 0;
    __syncthreads();

    int c1 = hdr[1]; if (c1 > CAP1) c1 = CAP1;
    for (int k = tid; k < c1; k += 256) {
        if (L1_dst[k] == bi) {
            int p = atomicAdd(&scnt, 1);
            if (p < CAPN) { esrc[p] = L1_src[k]; eea[p] = L1_ea[k]; }
        }
    }
    __syncthreads();
    int nE = scnt; if (nE > CAPN) nE = CAPN;
    if (tid == 0) { esrc[nE] = v; eea[nE] = eam; }   // self-loop
    __syncthreads();
    nE += 1;

    // parallel gather of source features into LDS (all loads in flight at once)
    for (int j = tid; j < nE; j += 256) {
        int s = esrc[j];
        xsA[j] = x[2 * s];
        xsB[j] = x[2 * s + 1];
    }
    __syncthreads();

    float wl0 = Wl1[lane], wl1w = Wl1[64 + lane], bl = bl1[lane];
    float we = We1[lane], at = att1[lane];
    float xr = x[2 * v] * Wr1[lane] + x[2 * v + 1] * Wr1[64 + lane] + br1[lane];

    // phase 1: scores, edges strided across the 4 waves
    for (int k = wq; k < nE; k += 4) {
        float xl = xsA[k] * wl0 + xsB[k] * wl1w + bl;
        float ev = xl + xr + eea[k] * we;
        ev = ev > 0.f ? ev : 0.2f * ev;
        float p = ev * at;
        for (int o = 32; o >= 1; o >>= 1) p += __shfl_xor(p, o, 64);
        if (lane == 0) scores[k] = p;
    }
    __syncthreads();

    if (wq == 0) {
        float m = -3.4e38f;
        for (int k = lane; k < nE; k += 64) m = fmaxf(m, scores[k]);
        for (int o = 32; o >= 1; o >>= 1) m = fmaxf(m, __shfl_xor(m, o, 64));
        float d = 0.f;
        for (int k = lane; k < nE; k += 64) d += expf(scores[k] - m);
        for (int o = 32; o >= 1; o >>= 1) d += __shfl_xor(d, o, 64);
        if (lane == 0) { m_sh = m; d_sh = d; }
    }
    __syncthreads();
    float m = m_sh, dinv = 1.f / d_sh;

    // phase 2: weighted sum, split across waves then combined in LDS
    float acc = 0.f;
    for (int k = wq; k < nE; k += 4) {
        float xl = xsA[k] * wl0 + xsB[k] * wl1w + bl;
        acc += expf(scores[k] - m) * dinv * xl;
    }
    part[wq][lane] = acc;
    __syncthreads();
    if (tid < 64) {
        float h = part[0][lane] + part[1][lane] + part[2][lane] + part[3][lane] + b1[lane];
        h1[bi * 64 + lane] = h > 0.f ? h : 0.f;
    }
}

// layer-2 transforms for all S1 nodes: xl2[i] = Wl2^T h1[i] + bl2 ; xr2 for target.
// one 256-thread block per node, k-dim split 16-per-wave, combined in LDS.
__global__ __launch_bounds__(256)
void k_xl2(const float* __restrict__ Wl2, const float* __restrict__ bl2,
           const float* __restrict__ Wr2, const float* __restrict__ br2,
           const int* __restrict__ hdr, const float* __restrict__ h1,
           float* __restrict__ xl2, float* __restrict__ xr2) {
    int bi = blockIdx.x;
    if (bi >= hdr[2]) return;
    int tid = threadIdx.x, c = tid & 63, q = tid >> 6;
    __shared__ float hrow[64];
    __shared__ float part[4][64];
    if (tid < 64) hrow[tid] = h1[bi * 64 + tid];
    __syncthreads();

    float p = 0.f;
    int k0 = 16 * q;
    for (int k = k0; k < k0 + 16; k++) p += hrow[k] * Wl2[k * 64 + c];
    part[q][c] = p;
    __syncthreads();
    if (tid < 64) xl2[bi * 64 + c] = part[0][c] + part[1][c] + part[2][c] + part[3][c] + bl2[c];

    if (bi == 0) {   // target transform (S1 index 0)
        __syncthreads();
        float p2 = 0.f;
        for (int k = k0; k < k0 + 16; k++) p2 += hrow[k] * Wr2[k * 64 + c];
        part[q][c] = p2;
        __syncthreads();
        if (tid < 64) xr2[c] = part[0][c] + part[1][c] + part[2][c] + part[3][c] + br2[c];
    }
}

// final: scores + softmax + weighted sum at target, relu, 64x128 head.
__global__ __launch_bounds__(128)
void k_fin(const float* __restrict__ We2, const float* __restrict__ att2,
           const float* __restrict__ b2,
           const float* __restrict__ Wf, const float* __restrict__ bf,
           const int* __restrict__ hdr,
           const int* __restrict__ L2_s1idx, const float* __restrict__ L2_ea,
           const float* __restrict__ xl2, const float* __restrict__ xr2,
           int E, float* __restrict__ out) {
    int tid = threadIdx.x, lane = tid & 63;
    __shared__ float scores[CAP2 + 1];
    __shared__ float h2sh[64];
    float eam = ((const float*)hdr)[4] / (float)E;
    int nE2 = hdr[3];

    if (tid < 64) {
        float we = We2[lane], at = att2[lane], xr = xr2[lane];
        for (int j = 0; j <= nE2; j++) {
            int   idx = (j < nE2) ? L2_s1idx[j] : 0;
            float eav = (j < nE2) ? L2_ea[j]    : eam;
            float ev = xl2[idx * 64 + lane] + xr + eav * we;
            ev = ev > 0.f ? ev : 0.2f * ev;
            float p = ev * at;
            for (int o = 32; o >= 1; o >>= 1) p += __shfl_xor(p, o, 64);
            if (lane == 0) scores[j] = p;
        }
        int tot = nE2 + 1;
        float m = -3.4e38f;
        for (int j = lane; j < tot; j += 64) m = fmaxf(m, scores[j]);
        for (int o = 32; o >= 1; o >>= 1) m = fmaxf(m, __shfl_xor(m, o, 64));
        float d = 0.f;
        for (int j = lane; j < tot; j += 64) d += expf(scores[j] - m);
        for (int o = 32; o >= 1; o >>= 1) d += __shfl_xor(d, o, 64);

        float acc = 0.f;
        for (int j = 0; j < tot; j++) {
            int idx = (j < nE2) ? L2_s1idx[j] : 0;
            acc += expf(scores[j] - m) / d * xl2[idx * 64 + lane];
        }
        float h = acc + b2[lane];
        h2sh[lane] = h > 0.f ? h : 0.f;
    }
    __syncthreads();

    // head: [64] @ [64,128] + bf, one thread per output
    float r = bf[tid];
    for (int c = 0; c < 64; c++) r += h2sh[c] * Wf[c * 128 + tid];
    out[tid] = r;
}

extern "C" void kernel_launch(void* const* d_in, const int* in_sizes, int n_in,
                              void* d_out, int out_size, void* d_ws, size_t ws_size,
                              hipStream_t stream) {
    const float* x    = (const float*)d_in[0];
    const int*   ei   = (const int*)  d_in[1];
    const float* ea   = (const float*)d_in[2];
    const int*   tptr = (const int*)  d_in[3];
    const float* Wl1  = (const float*)d_in[4];
    const float* bl1  = (const float*)d_in[5];
    const float* Wr1  = (const float*)d_in[6];
    const float* br1  = (const float*)d_in[7];
    const float* We1  = (const float*)d_in[8];
    const float* att1 = (const float*)d_in[9];
    const float* b1   = (const float*)d_in[10];
    const float* Wl2  = (const float*)d_in[11];
    const float* bl2  = (const float*)d_in[12];
    const float* Wr2  = (const float*)d_in[13];
    const float* br2  = (const float*)d_in[14];
    const float* We2  = (const float*)d_in[15];
    const float* att2 = (const float*)d_in[16];
    const float* b2   = (const float*)d_in[17];
    const float* Wf   = (const float*)d_in[18];
    const float* bf   = (const float*)d_in[19];

    int N = in_sizes[0] / 2;
    int E = in_sizes[2];

    char* base = (char*)d_ws;
    int*   hdr      = (int*)base;   base += 256;
    int*   node2idx = (int*)base;   base += (size_t)N * sizeof(int);
    int*   S1nodes  = (int*)base;   base += CAPS1 * sizeof(int);
    int*   L2_src   = (int*)base;   base += CAP2 * sizeof(int);
    int*   L2_s1idx = (int*)base;   base += CAP2 * sizeof(int);
    float* L2_ea    = (float*)base; base += CAP2 * sizeof(float);
    int*   L1_src   = (int*)base;   base += CAP1 * sizeof(int);
    int*   L1_dst   = (int*)base;   base += CAP1 * sizeof(int);
    float* L1_ea    = (float*)base; base += CAP1 * sizeof(float);
    float* h1       = (float*)base; base += (size_t)CAPS1 * 64 * sizeof(float);
    float* xl2      = (float*)base; base += (size_t)CAPS1 * 64 * sizeof(float);
    float* xr2      = (float*)base; base += 64 * sizeof(float);

    hipLaunchKernelGGL(k_init, dim3((N + 255) / 256), dim3(256), 0, stream,
                       hdr, node2idx, N);
    hipLaunchKernelGGL(k_scanA, dim3(1024), dim3(256), 0, stream,
                       ei, ea, tptr, E, hdr, L2_src, L2_ea);
    hipLaunchKernelGGL(k_build, dim3(1), dim3(64), 0, stream,
                       tptr, hdr, L2_src, L2_s1idx, node2idx, S1nodes);
    hipLaunchKernelGGL(k_scanC, dim3(1024), dim3(256), 0, stream,
                       ei, ea, E, node2idx, hdr, L1_src, L1_dst, L1_ea);
    hipLaunchKernelGGL(k_layer1, dim3(CAPS1), dim3(256), 0, stream,
                       x, Wl1, bl1, Wr1, br1, We1, att1, b1,
                       hdr, S1nodes, L1_src, L1_dst, L1_ea, h1, E);
    hipLaunchKernelGGL(k_xl2, dim3(CAPS1), dim3(256), 0, stream,
                       Wl2, bl2, Wr2, br2, hdr, h1, xl2, xr2);
    hipLaunchKernelGGL(k_fin, dim3(1), dim3(128), 0, stream,
                       We2, att2, b2, Wf, bf, hdr, L2_s1idx, L2_ea,
                       xl2, xr2, E, (float*)d_out);
}

// Round 3
// 170.140 us; speedup vs baseline: 1.5810x; 1.1874x over previous
//
#include <hip/hip_runtime.h>
#include <math.h>

#define CAP2   512           // max in-edges of target node (expected ~16)
#define CAPS1  (CAP2 + 1)    // max 1-hop node set size
#define CAP1   65536         // max edges into S1 nodes (expected ~300)
#define CAPN   512           // per-node in-edge cap inside layer-1 kernel
#define NBLK   1024          // scan grid blocks

// header (ints): [0]=cnt2  [2]=n_s1  [3]=nE2  [4]=ea_sum(float bits)  [8]=cnt1

__global__ void k_init(int* hdr) {
    int i = threadIdx.x;
    if (i < 64) hdr[i] = 0;
}

// scan 1: find in-edges of target t; per-block partial of sum(edge_attr)
__global__ __launch_bounds__(256)
void k_scanA(const int* __restrict__ ei, const float* __restrict__ ea,
             const int* __restrict__ tptr, int E,
             int* hdr, int* L2_src, float* L2_ea, float* partials) {
    int t = tptr[0];
    float local = 0.f;
    int stride = gridDim.x * blockDim.x;
    int gid = blockIdx.x * blockDim.x + threadIdx.x;
    const int4*   dst4 = (const int4*)(ei + E);
    const float4* ea4  = (const float4*)ea;
    int E4 = E >> 2;
    for (int e4 = gid; e4 < E4; e4 += stride) {
        int4 d = dst4[e4];
        float4 a = ea4[e4];
        local += a.x + a.y + a.z + a.w;
        int eb = e4 * 4;
        if (d.x == t) { int p = atomicAdd(&hdr[0], 1); if (p < CAP2) { L2_src[p] = ei[eb];     L2_ea[p] = a.x; } }
        if (d.y == t) { int p = atomicAdd(&hdr[0], 1); if (p < CAP2) { L2_src[p] = ei[eb + 1]; L2_ea[p] = a.y; } }
        if (d.z == t) { int p = atomicAdd(&hdr[0], 1); if (p < CAP2) { L2_src[p] = ei[eb + 2]; L2_ea[p] = a.z; } }
        if (d.w == t) { int p = atomicAdd(&hdr[0], 1); if (p < CAP2) { L2_src[p] = ei[eb + 3]; L2_ea[p] = a.w; } }
    }
    if (gid == 0) {                      // tail (E % 4)
        for (int e = E4 * 4; e < E; e++) {
            float a = ea[e];
            local += a;
            if (ei[E + e] == t) { int p = atomicAdd(&hdr[0], 1); if (p < CAP2) { L2_src[p] = ei[e]; L2_ea[p] = a; } }
        }
    }
    // block-level reduction -> one plain store per block (NO contended atomic)
    __shared__ float wsum[4];
    for (int o = 32; o >= 1; o >>= 1) local += __shfl_xor(local, o, 64);
    if ((threadIdx.x & 63) == 0) wsum[threadIdx.x >> 6] = local;
    __syncthreads();
    if (threadIdx.x == 0)
        partials[blockIdx.x] = wsum[0] + wsum[1] + wsum[2] + wsum[3];
}

// reduce partials (256 threads) + serial dedupe of S1 (thread 0, in LDS)
__global__ __launch_bounds__(256)
void k_build(const int* __restrict__ tptr, int* hdr,
             const float* __restrict__ partials,
             const int* __restrict__ L2_src,
             int* L2_s1idx, int* S1nodes) {
    int tid = threadIdx.x;
    __shared__ float wsum[4];
    __shared__ int   s1tmp[CAPS1];
    float local = partials[tid] + partials[tid + 256] +
                  partials[tid + 512] + partials[tid + 768];
    for (int o = 32; o >= 1; o >>= 1) local += __shfl_xor(local, o, 64);
    if ((tid & 63) == 0) wsum[tid >> 6] = local;
    __syncthreads();
    if (tid == 0) {
        ((float*)hdr)[4] = wsum[0] + wsum[1] + wsum[2] + wsum[3];
        int t = tptr[0];
        s1tmp[0] = t;
        int n = 1;
        int c2 = hdr[0]; if (c2 > CAP2) c2 = CAP2;
        for (int k = 0; k < c2; k++) {
            int v = L2_src[k];
            int idx = -1;
            for (int j = 0; j < n; j++) if (s1tmp[j] == v) { idx = j; break; }
            if (idx < 0) { idx = n; s1tmp[n] = v; n++; }
            L2_s1idx[k] = idx;
        }
        hdr[2] = n;
        hdr[3] = c2;
        for (int j = 0; j < n; j++) S1nodes[j] = s1tmp[j];
    }
}

// scan 2: collect all edges whose dst is in S1 (membership via LDS linear scan)
__global__ __launch_bounds__(256)
void k_scanC(const int* __restrict__ ei, const float* __restrict__ ea,
             int E, const int* __restrict__ hdr, const int* __restrict__ S1nodes,
             int* hdr_mut, int* L1_src, int* L1_dst, float* L1_ea) {
    __shared__ int s1[CAPS1];
    int n = hdr[2];
    for (int j = threadIdx.x; j < n; j += 256) s1[j] = S1nodes[j];
    __syncthreads();

    int stride = gridDim.x * blockDim.x;
    int gid = blockIdx.x * blockDim.x + threadIdx.x;
    const int4* dst4 = (const int4*)(ei + E);
    int E4 = E >> 2;
    for (int e4 = gid; e4 < E4; e4 += stride) {
        int4 d = dst4[e4];
        int eb = e4 * 4;
        int dd[4] = {d.x, d.y, d.z, d.w};
        #pragma unroll
        for (int q = 0; q < 4; q++) {
            int idx = -1;
            for (int j = 0; j < n; j++) if (s1[j] == dd[q]) { idx = j; break; }
            if (idx >= 0) {
                int p = atomicAdd(&hdr_mut[8], 1);
                if (p < CAP1) { L1_src[p] = ei[eb + q]; L1_dst[p] = idx; L1_ea[p] = ea[eb + q]; }
            }
        }
    }
    if (gid == 0) {
        for (int e = E4 * 4; e < E; e++) {
            int dv = ei[E + e];
            int idx = -1;
            for (int j = 0; j < n; j++) if (s1[j] == dv) { idx = j; break; }
            if (idx >= 0) {
                int p = atomicAdd(&hdr_mut[8], 1);
                if (p < CAP1) { L1_src[p] = ei[e]; L1_dst[p] = idx; L1_ea[p] = ea[e]; }
            }
        }
    }
}

// layer 1 (+ fused layer-2 input transforms): one 256-thread block per S1 node.
// lane = output channel; edges split across 4 waves; x gathered into LDS.
__global__ __launch_bounds__(256)
void k_layer1(const float* __restrict__ x,
              const float* __restrict__ Wl1, const float* __restrict__ bl1,
              const float* __restrict__ Wr1, const float* __restrict__ br1,
              const float* __restrict__ We1, const float* __restrict__ att1,
              const float* __restrict__ b1,
              const float* __restrict__ Wl2, const float* __restrict__ bl2,
              const float* __restrict__ Wr2, const float* __restrict__ br2,
              const int* __restrict__ hdr, const int* __restrict__ S1nodes,
              const int* __restrict__ L1_src, const int* __restrict__ L1_dst,
              const float* __restrict__ L1_ea,
              float* __restrict__ xl2, float* __restrict__ xr2, int E) {
    int bi = blockIdx.x;
    if (bi >= hdr[2]) return;
    int tid = threadIdx.x, lane = tid & 63, wq = tid >> 6;
    int v = S1nodes[bi];
    float eam = ((const float*)hdr)[4] / (float)E;

    __shared__ int   esrc[CAPN + 1];
    __shared__ float eea[CAPN + 1];
    __shared__ float xsA[CAPN + 1], xsB[CAPN + 1];
    __shared__ float scores[CAPN + 1];
    __shared__ float part[4][64];
    __shared__ float hrow[64];
    __shared__ float m_sh, d_sh;
    __shared__ int   scnt;
    if (tid == 0) scnt = 0;
    __syncthreads();

    int c1 = hdr[8]; if (c1 > CAP1) c1 = CAP1;
    for (int k = tid; k < c1; k += 256) {
        if (L1_dst[k] == bi) {
            int p = atomicAdd(&scnt, 1);
            if (p < CAPN) { esrc[p] = L1_src[k]; eea[p] = L1_ea[k]; }
        }
    }
    __syncthreads();
    int nE = scnt; if (nE > CAPN) nE = CAPN;
    if (tid == 0) { esrc[nE] = v; eea[nE] = eam; }   // self-loop
    __syncthreads();
    nE += 1;

    for (int j = tid; j < nE; j += 256) {            // parallel x gather
        int s = esrc[j];
        xsA[j] = x[2 * s];
        xsB[j] = x[2 * s + 1];
    }
    __syncthreads();

    float wl0 = Wl1[lane], wl1w = Wl1[64 + lane], bl = bl1[lane];
    float we = We1[lane], at = att1[lane];
    float xr = x[2 * v] * Wr1[lane] + x[2 * v + 1] * Wr1[64 + lane] + br1[lane];

    for (int k = wq; k < nE; k += 4) {               // scores
        float xl = xsA[k] * wl0 + xsB[k] * wl1w + bl;
        float ev = xl + xr + eea[k] * we;
        ev = ev > 0.f ? ev : 0.2f * ev;
        float p = ev * at;
        for (int o = 32; o >= 1; o >>= 1) p += __shfl_xor(p, o, 64);
        if (lane == 0) scores[k] = p;
    }
    __syncthreads();

    if (wq == 0) {                                   // softmax stats
        float m = -3.4e38f;
        for (int k = lane; k < nE; k += 64) m = fmaxf(m, scores[k]);
        for (int o = 32; o >= 1; o >>= 1) m = fmaxf(m, __shfl_xor(m, o, 64));
        float d = 0.f;
        for (int k = lane; k < nE; k += 64) d += expf(scores[k] - m);
        for (int o = 32; o >= 1; o >>= 1) d += __shfl_xor(d, o, 64);
        if (lane == 0) { m_sh = m; d_sh = d; }
    }
    __syncthreads();
    float m = m_sh, dinv = 1.f / d_sh;

    float acc = 0.f;                                 // weighted sum
    for (int k = wq; k < nE; k += 4) {
        float xl = xsA[k] * wl0 + xsB[k] * wl1w + bl;
        acc += expf(scores[k] - m) * dinv * xl;
    }
    part[wq][lane] = acc;
    __syncthreads();
    if (tid < 64) {
        float h = part[0][lane] + part[1][lane] + part[2][lane] + part[3][lane] + b1[lane];
        hrow[lane] = h > 0.f ? h : 0.f;
    }
    __syncthreads();

    // fused: xl2[bi] = Wl2^T hrow + bl2 (k-split across waves)
    float p = 0.f;
    int k0 = 16 * wq;
    for (int k = k0; k < k0 + 16; k++) p += hrow[k] * Wl2[k * 64 + lane];
    part[wq][lane] = p;
    __syncthreads();
    if (tid < 64)
        xl2[bi * 64 + lane] = part[0][lane] + part[1][lane] + part[2][lane] + part[3][lane] + bl2[lane];

    if (bi == 0) {                                   // target transform
        __syncthreads();
        float p2 = 0.f;
        for (int k = k0; k < k0 + 16; k++) p2 += hrow[k] * Wr2[k * 64 + lane];
        part[wq][lane] = p2;
        __syncthreads();
        if (tid < 64)
            xr2[lane] = part[0][lane] + part[1][lane] + part[2][lane] + part[3][lane] + br2[lane];
    }
}

// final: scores + softmax + weighted sum at target, relu, 64x128 head.
__global__ __launch_bounds__(128)
void k_fin(const float* __restrict__ We2, const float* __restrict__ att2,
           const float* __restrict__ b2,
           const float* __restrict__ Wf, const float* __restrict__ bf,
           const int* __restrict__ hdr,
           const int* __restrict__ L2_s1idx, const float* __restrict__ L2_ea,
           const float* __restrict__ xl2, const float* __restrict__ xr2,
           int E, float* __restrict__ out) {
    int tid = threadIdx.x, lane = tid & 63;
    __shared__ float scores[CAP2 + 1];
    __shared__ float h2sh[64];
    float eam = ((const float*)hdr)[4] / (float)E;
    int nE2 = hdr[3];

    if (tid < 64) {
        float we = We2[lane], at = att2[lane], xr = xr2[lane];
        for (int j = 0; j <= nE2; j++) {
            int   idx = (j < nE2) ? L2_s1idx[j] : 0;
            float eav = (j < nE2) ? L2_ea[j]    : eam;
            float ev = xl2[idx * 64 + lane] + xr + eav * we;
            ev = ev > 0.f ? ev : 0.2f * ev;
            float p = ev * at;
            for (int o = 32; o >= 1; o >>= 1) p += __shfl_xor(p, o, 64);
            if (lane == 0) scores[j] = p;
        }
        int tot = nE2 + 1;
        float m = -3.4e38f;
        for (int j = lane; j < tot; j += 64) m = fmaxf(m, scores[j]);
        for (int o = 32; o >= 1; o >>= 1) m = fmaxf(m, __shfl_xor(m, o, 64));
        float d = 0.f;
        for (int j = lane; j < tot; j += 64) d += expf(scores[j] - m);
        for (int o = 32; o >= 1; o >>= 1) d += __shfl_xor(d, o, 64);

        float acc = 0.f;
        for (int j = 0; j < tot; j++) {
            int idx = (j < nE2) ? L2_s1idx[j] : 0;
            acc += expf(scores[j] - m) / d * xl2[idx * 64 + lane];
        }
        float h = acc + b2[lane];
        h2sh[lane] = h > 0.f ? h : 0.f;
    }
    __syncthreads();

    float r = bf[tid];
    for (int c = 0; c < 64; c++) r += h2sh[c] * Wf[c * 128 + tid];
    out[tid] = r;
}

extern "C" void kernel_launch(void* const* d_in, const int* in_sizes, int n_in,
                              void* d_out, int out_size, void* d_ws, size_t ws_size,
                              hipStream_t stream) {
    const float* x    = (const float*)d_in[0];
    const int*   ei   = (const int*)  d_in[1];
    const float* ea   = (const float*)d_in[2];
    const int*   tptr = (const int*)  d_in[3];
    const float* Wl1  = (const float*)d_in[4];
    const float* bl1  = (const float*)d_in[5];
    const float* Wr1  = (const float*)d_in[6];
    const float* br1  = (const float*)d_in[7];
    const float* We1  = (const float*)d_in[8];
    const float* att1 = (const float*)d_in[9];
    const float* b1   = (const float*)d_in[10];
    const float* Wl2  = (const float*)d_in[11];
    const float* bl2  = (const float*)d_in[12];
    const float* Wr2  = (const float*)d_in[13];
    const float* br2  = (const float*)d_in[14];
    const float* We2  = (const float*)d_in[15];
    const float* att2 = (const float*)d_in[16];
    const float* b2   = (const float*)d_in[17];
    const float* Wf   = (const float*)d_in[18];
    const float* bf   = (const float*)d_in[19];

    int E = in_sizes[2];

    char* base = (char*)d_ws;
    int*   hdr      = (int*)base;   base += 256;
    float* partials = (float*)base; base += NBLK * sizeof(float);
    int*   S1nodes  = (int*)base;   base += CAPS1 * sizeof(int);
    int*   L2_src   = (int*)base;   base += CAP2 * sizeof(int);
    int*   L2_s1idx = (int*)base;   base += CAP2 * sizeof(int);
    float* L2_ea    = (float*)base; base += CAP2 * sizeof(float);
    int*   L1_src   = (int*)base;   base += CAP1 * sizeof(int);
    int*   L1_dst   = (int*)base;   base += CAP1 * sizeof(int);
    float* L1_ea    = (float*)base; base += CAP1 * sizeof(float);
    float* xl2      = (float*)base; base += (size_t)CAPS1 * 64 * sizeof(float);
    float* xr2      = (float*)base; base += 64 * sizeof(float);

    hipLaunchKernelGGL(k_init, dim3(1), dim3(64), 0, stream, hdr);
    hipLaunchKernelGGL(k_scanA, dim3(NBLK), dim3(256), 0, stream,
                       ei, ea, tptr, E, hdr, L2_src, L2_ea, partials);
    hipLaunchKernelGGL(k_build, dim3(1), dim3(256), 0, stream,
                       tptr, hdr, partials, L2_src, L2_s1idx, S1nodes);
    hipLaunchKernelGGL(k_scanC, dim3(NBLK), dim3(256), 0, stream,
                       ei, ea, E, hdr, S1nodes, hdr, L1_src, L1_dst, L1_ea);
    hipLaunchKernelGGL(k_layer1, dim3(CAPS1), dim3(256), 0, stream,
                       x, Wl1, bl1, Wr1, br1, We1, att1, b1,
                       Wl2, bl2, Wr2, br2,
                       hdr, S1nodes, L1_src, L1_dst, L1_ea, xl2, xr2, E);
    hipLaunchKernelGGL(k_fin, dim3(1), dim3(128), 0, stream,
                       We2, att2, b2, Wf, bf, hdr, L2_s1idx, L2_ea,
                       xl2, xr2, E, (float*)d_out);
}